// Round 1
// baseline (289.955 us; speedup 1.0000x reference)
//
#include <hip/hip_runtime.h>
#include <hip/hip_bf16.h>

// Problem constants (from reference)
#define NUM_HEADS 8
#define HEAD_DIM 64
#define Q_LEN 16
#define HIDDEN 512
#define NUM_LOGICAL 2048
#define BLOCK_SZ 16           // kv positions per physical block
#define NCHUNK 128            // kv chunks for split-softmax
#define CBLK 16               // logical blocks per chunk (128*16 = 2048)
#define KSTRIDE 68            // padded LDS row stride (floats); 272B = 16B-aligned, 2-way max bank alias

// ---------------------------------------------------------------------------
// proj: out[s][o] = scale * (bias[o] + sum_k in[s][k] * W[o][k])
// One wave per output column o; 16 s rows per wave; coalesced float4 loads.
// ---------------------------------------------------------------------------
__global__ __launch_bounds__(256) void proj_kernel(
    const float* __restrict__ in,    // [16][512]
    const float* __restrict__ W,     // [512][512] (row o contiguous)
    const float* __restrict__ bias,  // [512]
    float* __restrict__ out,         // [16][512]
    float scale) {
  const int t = threadIdx.x;
  const int lane = t & 63;
  const int wave = t >> 6;
  const int o = blockIdx.x * 4 + wave;  // 128 blocks * 4 waves = 512 columns

  const float4 w0 = *reinterpret_cast<const float4*>(W + o * HIDDEN + lane * 8);
  const float4 w1 = *reinterpret_cast<const float4*>(W + o * HIDDEN + lane * 8 + 4);

  float acc[Q_LEN];
#pragma unroll
  for (int s = 0; s < Q_LEN; ++s) {
    const float4 a0 = *reinterpret_cast<const float4*>(in + s * HIDDEN + lane * 8);
    const float4 a1 = *reinterpret_cast<const float4*>(in + s * HIDDEN + lane * 8 + 4);
    acc[s] = a0.x * w0.x + a0.y * w0.y + a0.z * w0.z + a0.w * w0.w +
             a1.x * w1.x + a1.y * w1.y + a1.z * w1.z + a1.w * w1.w;
  }
#pragma unroll
  for (int s = 0; s < Q_LEN; ++s) {
    float v = acc[s];
#pragma unroll
    for (int off = 32; off; off >>= 1) v += __shfl_xor(v, off, 64);
    if (lane == 0) out[s * HIDDEN + o] = scale * (v + bias[o]);
  }
}

// ---------------------------------------------------------------------------
// attn: one WG per (head, kv-chunk). 256 threads = 4 waves.
// Thread t: i = t>>4 (q row), jd = t&15 (j for scores / d-slice for PV).
// Online softmax per chunk; partials (m, l, unnormalized O) to workspace.
// ---------------------------------------------------------------------------
__global__ __launch_bounds__(256) void attn_kernel(
    const float* __restrict__ kcache,  // [NB][H][16][64]
    const float* __restrict__ vcache,
    const float* __restrict__ qbuf,    // [16][512], already *0.125
    const int* __restrict__ btab,      // [2048] int32
    float* __restrict__ Opart,         // [H][NCHUNK][16][64]
    float* __restrict__ mpart,         // [H][NCHUNK][16]
    float* __restrict__ lpart) {       // [H][NCHUNK][16]
  const int wg = blockIdx.x;
  const int head = wg >> 7;            // / NCHUNK
  const int chunk = wg & (NCHUNK - 1);
  const int t = threadIdx.x;
  const int i = t >> 4;                // q row 0..15
  const int jd = t & 15;               // score col / PV d-slice
  const int lane = t & 63;
  const int grp = lane & 48;           // base lane of this row's 16-lane group

  __shared__ float k_lds[BLOCK_SZ][KSTRIDE];
  __shared__ float v_lds[BLOCK_SZ][KSTRIDE];

  // q row for this thread's i, this head: 64 floats in registers
  float4 qreg[16];
  {
    const float* qrow = qbuf + i * HIDDEN + head * HEAD_DIM;
#pragma unroll
    for (int x = 0; x < 16; ++x)
      qreg[x] = *reinterpret_cast<const float4*>(qrow + x * 4);
  }

  float m_i = -1e30f, l_i = 0.0f;
  float4 o_acc = {0.f, 0.f, 0.f, 0.f};

  const int base_blk = chunk * CBLK;
  const int srow = t >> 4;
  const int scol = (t & 15) * 4;

  // prefetch block 0 into registers
  long long phys = btab[base_blk];
  float4 kreg = *reinterpret_cast<const float4*>(
      kcache + (phys * NUM_HEADS + head) * (BLOCK_SZ * HEAD_DIM) + t * 4);
  float4 vreg = *reinterpret_cast<const float4*>(
      vcache + (phys * NUM_HEADS + head) * (BLOCK_SZ * HEAD_DIM) + t * 4);

  for (int b = 0; b < CBLK; ++b) {
    __syncthreads();  // previous iteration's LDS reads complete
    *reinterpret_cast<float4*>(&k_lds[srow][scol]) = kreg;
    *reinterpret_cast<float4*>(&v_lds[srow][scol]) = vreg;
    if (b + 1 < CBLK) {  // prefetch next block (latency hidden by compute)
      long long ph = btab[base_blk + b + 1];
      kreg = *reinterpret_cast<const float4*>(
          kcache + (ph * NUM_HEADS + head) * (BLOCK_SZ * HEAD_DIM) + t * 4);
      vreg = *reinterpret_cast<const float4*>(
          vcache + (ph * NUM_HEADS + head) * (BLOCK_SZ * HEAD_DIM) + t * 4);
    }
    __syncthreads();  // staged tile visible

    // ---- scores: s[i][jd] = q[i] . k[jd]  (q pre-scaled by 1/8)
    float s = 0.0f;
#pragma unroll
    for (int x = 0; x < 16; ++x) {
      const float4 kk = *reinterpret_cast<const float4*>(&k_lds[jd][x * 4]);
      s += qreg[x].x * kk.x + qreg[x].y * kk.y + qreg[x].z * kk.z + qreg[x].w * kk.w;
    }

    // ---- online softmax over this block's 16 columns (16-lane group reduce)
    float mx = s;
    mx = fmaxf(mx, __shfl_xor(mx, 1, 64));
    mx = fmaxf(mx, __shfl_xor(mx, 2, 64));
    mx = fmaxf(mx, __shfl_xor(mx, 4, 64));
    mx = fmaxf(mx, __shfl_xor(mx, 8, 64));
    const float m_new = fmaxf(m_i, mx);
    const float r = __expf(m_i - m_new);
    const float p = __expf(s - m_new);
    float ps = p;
    ps += __shfl_xor(ps, 1, 64);
    ps += __shfl_xor(ps, 2, 64);
    ps += __shfl_xor(ps, 4, 64);
    ps += __shfl_xor(ps, 8, 64);
    l_i = l_i * r + ps;
    m_i = m_new;

    // ---- PV: o_acc[i][jd*4..+3] += sum_j p[i][j] * v[j][jd*4..+3]
    o_acc.x *= r; o_acc.y *= r; o_acc.z *= r; o_acc.w *= r;
#pragma unroll
    for (int j = 0; j < 16; ++j) {
      const float pj = __shfl(p, grp | j, 64);  // p held by lane (grp|j), wave-local
      const float4 vv = *reinterpret_cast<const float4*>(&v_lds[j][jd * 4]);
      o_acc.x += pj * vv.x;
      o_acc.y += pj * vv.y;
      o_acc.z += pj * vv.z;
      o_acc.w += pj * vv.w;
    }
  }

  // write partials (unnormalized)
  float* op = Opart + ((size_t)(head * NCHUNK + chunk) * Q_LEN + i) * HEAD_DIM + jd * 4;
  *reinterpret_cast<float4*>(op) = o_acc;
  if (jd == 0) {
    mpart[(head * NCHUNK + chunk) * Q_LEN + i] = m_i;
    lpart[(head * NCHUNK + chunk) * Q_LEN + i] = l_i;
  }
}

// ---------------------------------------------------------------------------
// reduce: combine NCHUNK partials per (head, q-row). One wave per row.
// ---------------------------------------------------------------------------
__global__ __launch_bounds__(256) void reduce_kernel(
    const float* __restrict__ Opart, const float* __restrict__ mpart,
    const float* __restrict__ lpart, float* __restrict__ ofinal /*[16][512]*/) {
  const int t = threadIdx.x;
  const int lane = t & 63;
  const int wave = t >> 6;
  const int r = blockIdx.x * 4 + wave;  // 32 blocks * 4 = 128 rows
  const int h = r >> 4, i = r & 15;

  const float* mrow = mpart + (size_t)h * NCHUNK * Q_LEN + i;  // stride Q_LEN per chunk
  float mx = fmaxf(mrow[lane * Q_LEN], mrow[(lane + 64) * Q_LEN]);
#pragma unroll
  for (int off = 32; off; off >>= 1) mx = fmaxf(mx, __shfl_xor(mx, off, 64));

  float oacc = 0.0f, L = 0.0f;
  for (int c = 0; c < NCHUNK; ++c) {
    const float w = __expf(mrow[c * Q_LEN] - mx);
    L += w * lpart[((size_t)h * NCHUNK + c) * Q_LEN + i];
    oacc += w * Opart[(((size_t)h * NCHUNK + c) * Q_LEN + i) * HEAD_DIM + lane];
  }
  ofinal[i * HIDDEN + h * HEAD_DIM + lane] = oacc / L;
}

// ---------------------------------------------------------------------------
extern "C" void kernel_launch(void* const* d_in, const int* in_sizes, int n_in,
                              void* d_out, int out_size, void* d_ws, size_t ws_size,
                              hipStream_t stream) {
  const float* hidden = (const float*)d_in[0];   // [1][16][512]
  const float* kcache = (const float*)d_in[1];   // [4096][8][16][64]
  const float* vcache = (const float*)d_in[2];
  const float* Wq = (const float*)d_in[3];       // [512][512]
  const float* bq = (const float*)d_in[4];
  const float* Wo = (const float*)d_in[5];
  const float* bo = (const float*)d_in[6];
  const int* btab = (const int*)d_in[7];         // [2048] int32

  float* ws = (float*)d_ws;
  float* q_ws = ws;                                   // 16*512        = 8192
  float* Opart = q_ws + Q_LEN * HIDDEN;               // 8*128*16*64   = 1048576
  float* mpart = Opart + (size_t)NUM_HEADS * NCHUNK * Q_LEN * HEAD_DIM;  // 16384
  float* lpart = mpart + NUM_HEADS * NCHUNK * Q_LEN;  // 16384
  float* ofin = lpart + NUM_HEADS * NCHUNK * Q_LEN;   // 8192
  float* out = (float*)d_out;

  // 1) q projection (+bias, pre-scale by 1/sqrt(64))
  hipLaunchKernelGGL(proj_kernel, dim3(HIDDEN / 4), dim3(256), 0, stream,
                     hidden, Wq, bq, q_ws, 0.125f);
  // 2) paged attention, split-softmax over 128 kv chunks
  hipLaunchKernelGGL(attn_kernel, dim3(NUM_HEADS * NCHUNK), dim3(256), 0, stream,
                     kcache, vcache, q_ws, btab, Opart, mpart, lpart);
  // 3) combine chunk partials
  hipLaunchKernelGGL(reduce_kernel, dim3(NUM_HEADS * Q_LEN / 4), dim3(256), 0, stream,
                     Opart, mpart, lpart, ofin);
  // 4) output projection
  hipLaunchKernelGGL(proj_kernel, dim3(HIDDEN / 4), dim3(256), 0, stream,
                     ofin, Wo, bo, out, 1.0f);
}

// Round 5
// 289.626 us; speedup vs baseline: 1.0011x; 1.0011x over previous
//
#include <hip/hip_runtime.h>

// Problem constants
#define NUM_HEADS 8
#define HEAD_DIM 64
#define Q_LEN 16
#define HIDDEN 512
#define NCHUNK 256           // kv chunks per head (split-softmax tasks)
#define CBLK 8               // logical blocks per chunk (256*8 = 2048); 128 kv/task

typedef __attribute__((ext_vector_type(8))) short short8;  // 8 bf16
typedef __attribute__((ext_vector_type(4))) float f32x4;

__device__ __forceinline__ short f2bf(float x) {  // RNE f32->bf16
  unsigned u = __float_as_uint(x);
  return (short)((u + 0x7FFFu + ((u >> 16) & 1u)) >> 16);
}
__device__ __forceinline__ float bf2f(short b) {
  return __uint_as_float(((unsigned)(unsigned short)b) << 16);
}
// split 8 f32 into bf16 hi + lo (x = hi + lo + O(2^-18 x))
__device__ __forceinline__ void split8(f32x4 a, f32x4 b, short8& hi, short8& lo) {
#pragma unroll
  for (int e = 0; e < 4; ++e) {
    short h = f2bf(a[e]); hi[e] = h; lo[e] = f2bf(a[e] - bf2f(h));
  }
#pragma unroll
  for (int e = 0; e < 4; ++e) {
    short h = f2bf(b[e]); hi[4 + e] = h; lo[4 + e] = f2bf(b[e] - bf2f(h));
  }
}

// ---------------------------------------------------------------------------
// proj: out[s][o] = scale * (bias[o] + sum_k in[s][k] * W[o][k])  (R1-verified)
// ---------------------------------------------------------------------------
__global__ __launch_bounds__(256) void proj_kernel(
    const float* __restrict__ in, const float* __restrict__ W,
    const float* __restrict__ bias, float* __restrict__ out, float scale) {
  const int t = threadIdx.x;
  const int lane = t & 63;
  const int wave = t >> 6;
  const int o = blockIdx.x * 4 + wave;

  const float4 w0 = *reinterpret_cast<const float4*>(W + o * HIDDEN + lane * 8);
  const float4 w1 = *reinterpret_cast<const float4*>(W + o * HIDDEN + lane * 8 + 4);

  float acc[Q_LEN];
#pragma unroll
  for (int s = 0; s < Q_LEN; ++s) {
    const float4 a0 = *reinterpret_cast<const float4*>(in + s * HIDDEN + lane * 8);
    const float4 a1 = *reinterpret_cast<const float4*>(in + s * HIDDEN + lane * 8 + 4);
    acc[s] = a0.x * w0.x + a0.y * w0.y + a0.z * w0.z + a0.w * w0.w +
             a1.x * w1.x + a1.y * w1.y + a1.z * w1.z + a1.w * w1.w;
  }
#pragma unroll
  for (int s = 0; s < Q_LEN; ++s) {
    float v = acc[s];
#pragma unroll
    for (int off = 32; off; off >>= 1) v += __shfl_xor(v, off, 64);
    if (lane == 0) out[s * HIDDEN + o] = scale * (v + bias[o]);
  }
}

// ---------------------------------------------------------------------------
// attn: one WAVE per (head, chunk) task; 2048 tasks; flat softmax per task.
// Phase 1: QK^T for all 8 blocks -> 8 S-tiles in regs (MFMA, 3-term bf16 split)
// Phase 2: single LDS transpose (write-once, __syncthreads, read-once)
// Phase 3: flat row max/exp/sum
// Phase 4: PV (MFMA, 3-term split), V loaded direct in B-frag layout
// ---------------------------------------------------------------------------
__global__ __launch_bounds__(256) void attn_kernel(
    const float* __restrict__ kcache, const float* __restrict__ vcache,
    const float* __restrict__ qbuf, const int* __restrict__ btab,
    float* __restrict__ Opart, float* __restrict__ mpart,
    float* __restrict__ lpart) {
  const int tid = threadIdx.x;
  const int wv = tid >> 6;
  const int lane = tid & 63;
  const int cr = lane & 15;     // row/col index within 16
  const int cg = lane >> 4;     // lane group 0..3
  const int wid = blockIdx.x * 4 + wv;
  const int head = wid >> 8;           // / NCHUNK
  const int chunk = wid & (NCHUNK - 1);

  __shared__ float s_lds[4][16][132];  // per-wave transpose buffer
  float(*sl)[132] = s_lds[wv];

  // Q fragments (A-layout): lane holds q[row=cr][k-slice cg*8.. within each 32]
  short8 qh[2], ql[2];
  {
    const float* qr = qbuf + cr * HIDDEN + head * HEAD_DIM + cg * 8;
#pragma unroll
    for (int m = 0; m < 2; ++m) {
      f32x4 a = *reinterpret_cast<const f32x4*>(qr + m * 32);
      f32x4 b = *reinterpret_cast<const f32x4*>(qr + m * 32 + 4);
      split8(a, b, qh[m], ql[m]);
    }
  }

  const int cbase = chunk * CBLK;
  int bsv[CBLK];
#pragma unroll
  for (int i = 0; i < CBLK; ++i) bsv[i] = btab[cbase + i];

  // ---- Phase 1: QK^T, 8 S-tiles (tile = block; cols j16 = lane&15)
  f32x4 acc[8];
#pragma unroll
  for (int i = 0; i < 8; ++i) acc[i] = f32x4{0.f, 0.f, 0.f, 0.f};
#pragma unroll
  for (int it = 0; it < CBLK; ++it) {
    const float* kb = kcache + ((size_t)bsv[it] * NUM_HEADS + head) * 1024 + cr * 64 + cg * 8;
#pragma unroll
    for (int m = 0; m < 2; ++m) {
      f32x4 ka = *reinterpret_cast<const f32x4*>(kb + m * 32);
      f32x4 kbv = *reinterpret_cast<const f32x4*>(kb + m * 32 + 4);
      short8 kh, kl;
      split8(ka, kbv, kh, kl);
      acc[it] = __builtin_amdgcn_mfma_f32_16x16x32_bf16(qh[m], kh, acc[it], 0, 0, 0);
      acc[it] = __builtin_amdgcn_mfma_f32_16x16x32_bf16(ql[m], kh, acc[it], 0, 0, 0);
      acc[it] = __builtin_amdgcn_mfma_f32_16x16x32_bf16(qh[m], kl, acc[it], 0, 0, 0);
    }
  }

  // ---- Phase 2: transpose S (D-layout -> row-owned layout) via LDS, once
  // D-layout (verified m89/m91): col = lane&15, row = (lane>>4)*4 + reg
#pragma unroll
  for (int tile = 0; tile < 8; ++tile)
#pragma unroll
    for (int r = 0; r < 4; ++r) sl[cg * 4 + r][tile * 16 + cr] = acc[tile][r];
  __syncthreads();
  f32x4 p[8];  // lane holds S[row=cr][j = jg*32 + cg*8 + e] for jg=0..3
#pragma unroll
  for (int jg = 0; jg < 4; ++jg) {
    p[jg * 2] = *reinterpret_cast<const f32x4*>(&sl[cr][jg * 32 + cg * 8]);
    p[jg * 2 + 1] = *reinterpret_cast<const f32x4*>(&sl[cr][jg * 32 + cg * 8 + 4]);
  }

  // ---- Phase 3: flat softmax over the task's 128 cols of row cr
  float mx = p[0][0];
#pragma unroll
  for (int x = 0; x < 8; ++x)
#pragma unroll
    for (int e = 0; e < 4; ++e) mx = fmaxf(mx, p[x][e]);
  mx = fmaxf(mx, __shfl_xor(mx, 16, 64));
  mx = fmaxf(mx, __shfl_xor(mx, 32, 64));
  float l = 0.f;
#pragma unroll
  for (int x = 0; x < 8; ++x)
#pragma unroll
    for (int e = 0; e < 4; ++e) {
      p[x][e] = __expf(p[x][e] - mx);
      l += p[x][e];
    }
  l += __shfl_xor(l, 16, 64);
  l += __shfl_xor(l, 32, 64);

  // ---- Phase 4: PV. A = P (row cr, k-slice cg*8+e per jg), B = V columns
  f32x4 o[4] = {f32x4{0,0,0,0}, f32x4{0,0,0,0}, f32x4{0,0,0,0}, f32x4{0,0,0,0}};
#pragma unroll
  for (int jg = 0; jg < 4; ++jg) {
    short8 ph, pl;
    split8(p[jg * 2], p[jg * 2 + 1], ph, pl);
    // j = jg*32 + cg*8 + e -> block bsv[jg*2 + (cg>>1)], row (cg&1)*8+e, col t*16+cr
    const int bj = (cg < 2) ? bsv[jg * 2] : bsv[jg * 2 + 1];
    const float* vb = vcache + ((size_t)bj * NUM_HEADS + head) * 1024 + ((cg & 1) * 8) * 64 + cr;
#pragma unroll
    for (int t = 0; t < 4; ++t) {
      float vf[8];
#pragma unroll
      for (int e = 0; e < 8; ++e) vf[e] = vb[e * 64 + t * 16];
      f32x4 va = {vf[0], vf[1], vf[2], vf[3]};
      f32x4 vbv = {vf[4], vf[5], vf[6], vf[7]};
      short8 vh, vl;
      split8(va, vbv, vh, vl);
      o[t] = __builtin_amdgcn_mfma_f32_16x16x32_bf16(ph, vh, o[t], 0, 0, 0);
      o[t] = __builtin_amdgcn_mfma_f32_16x16x32_bf16(ph, vl, o[t], 0, 0, 0);
      o[t] = __builtin_amdgcn_mfma_f32_16x16x32_bf16(pl, vh, o[t], 0, 0, 0);
    }
  }

  // ---- write unnormalized partials; o D-layout: row cg*4+r, col t*16+cr
  float* ob = Opart + ((size_t)(head * NCHUNK + chunk) * Q_LEN + cg * 4) * HEAD_DIM + cr;
#pragma unroll
  for (int r = 0; r < 4; ++r)
#pragma unroll
    for (int t = 0; t < 4; ++t) ob[r * HEAD_DIM + t * 16] = o[t][r];
  if (lane < 16) {  // lane == row for lanes 0..15
    mpart[(head * NCHUNK + chunk) * Q_LEN + lane] = mx;
    lpart[(head * NCHUNK + chunk) * Q_LEN + lane] = l;
  }
}

// ---------------------------------------------------------------------------
// reduce: ONE WG (4 waves) per (head, q-row) -> grid must be 128, not 32.
// (R3/R4 bug: launched with 32 WGs, heads 2..7 never reduced.)
// ---------------------------------------------------------------------------
__global__ __launch_bounds__(256) void reduce_kernel(
    const float* __restrict__ Opart, const float* __restrict__ mpart,
    const float* __restrict__ lpart, float* __restrict__ ofinal) {
  const int b = blockIdx.x;  // 128 = 8 heads x 16 rows
  const int h = b >> 4, i = b & 15;
  const int t = threadIdx.x, w = t >> 6, lane = t & 63;
  __shared__ float red[4][64];
  __shared__ float sml[8];

  const float* mrow = mpart + (size_t)h * NCHUNK * Q_LEN + i;
  const float* lrow = lpart + (size_t)h * NCHUNK * Q_LEN + i;

  float mx = -1e30f;
#pragma unroll 8
  for (int k = 0; k < 64; ++k) mx = fmaxf(mx, mrow[(w * 64 + k) * Q_LEN]);
  if (lane == 0) sml[w] = mx;
  __syncthreads();
  const float MX = fmaxf(fmaxf(sml[0], sml[1]), fmaxf(sml[2], sml[3]));

  float L = 0.0f, oa = 0.0f;
#pragma unroll 4
  for (int k = 0; k < 64; ++k) {
    const int c = w * 64 + k;
    const float wc = __expf(mrow[c * Q_LEN] - MX);
    L += wc * lrow[c * Q_LEN];
    oa += wc * Opart[(((size_t)h * NCHUNK + c) * Q_LEN + i) * HEAD_DIM + lane];
  }
  red[w][lane] = oa;
  if (lane == 0) sml[4 + w] = L;
  __syncthreads();
  if (w == 0) {
    const float osum = red[0][lane] + red[1][lane] + red[2][lane] + red[3][lane];
    const float Ls = sml[4] + sml[5] + sml[6] + sml[7];
    ofinal[i * HIDDEN + h * HEAD_DIM + lane] = osum / Ls;
  }
}

// ---------------------------------------------------------------------------
extern "C" void kernel_launch(void* const* d_in, const int* in_sizes, int n_in,
                              void* d_out, int out_size, void* d_ws, size_t ws_size,
                              hipStream_t stream) {
  const float* hidden = (const float*)d_in[0];
  const float* kcache = (const float*)d_in[1];
  const float* vcache = (const float*)d_in[2];
  const float* Wq = (const float*)d_in[3];
  const float* bq = (const float*)d_in[4];
  const float* Wo = (const float*)d_in[5];
  const float* bo = (const float*)d_in[6];
  const int* btab = (const int*)d_in[7];

  float* ws = (float*)d_ws;
  float* q_ws = ws;                                    // 16*512
  float* Opart = q_ws + Q_LEN * HIDDEN;                // 8*256*16*64 = 2097152
  float* mpart = Opart + (size_t)NUM_HEADS * NCHUNK * Q_LEN * HEAD_DIM;
  float* lpart = mpart + NUM_HEADS * NCHUNK * Q_LEN;   // 32768 each
  float* ofin = lpart + NUM_HEADS * NCHUNK * Q_LEN;
  float* out = (float*)d_out;

  hipLaunchKernelGGL(proj_kernel, dim3(HIDDEN / 4), dim3(256), 0, stream,
                     hidden, Wq, bq, q_ws, 0.125f);
  hipLaunchKernelGGL(attn_kernel, dim3(NUM_HEADS * NCHUNK / 4), dim3(256), 0, stream,
                     kcache, vcache, q_ws, btab, Opart, mpart, lpart);
  // FIX: one WG per (head, q-row) => 8*16 = 128 workgroups (was /4 = 32)
  hipLaunchKernelGGL(reduce_kernel, dim3(NUM_HEADS * Q_LEN), dim3(256), 0, stream,
                     Opart, mpart, lpart, ofin);
  hipLaunchKernelGGL(proj_kernel, dim3(HIDDEN / 4), dim3(256), 0, stream,
                     ofin, Wo, bo, out, 1.0f);
}